// Round 1
// baseline (1348.844 us; speedup 1.0000x reference)
//
#include <hip/hip_runtime.h>
#include <math.h>

#define S_LEN 2048
#define NB 2
#define NH 16
#define DH 64

// thetas[p] = 10^-p as fp32 (matches numpy fp32 rounding to ~1ulp; angle error negligible)
__constant__ float c_thetas[32] = {
  1e0f,  1e-1f,  1e-2f,  1e-3f,  1e-4f,  1e-5f,  1e-6f,  1e-7f,
  1e-8f, 1e-9f,  1e-10f, 1e-11f, 1e-12f, 1e-13f, 1e-14f, 1e-15f,
  1e-16f,1e-17f, 1e-18f, 1e-19f, 1e-20f, 1e-21f, 1e-22f, 1e-23f,
  1e-24f,1e-25f, 1e-26f, 1e-27f, 1e-28f, 1e-29f, 1e-30f, 1e-31f
};

// ---------------------------------------------------------------------------
// Generic fp32 GEMM: C[M,N] = A[M,K] @ B[K,N]. Tile 64x64, K-tile 16,
// 256 threads, 4x4 accum/thread. LDS stride 68 keeps float4 alignment
// (272 B rows) and <=2-way bank conflicts (free per m136).
// ---------------------------------------------------------------------------
__global__ __launch_bounds__(256) void gemm_f32(const float* __restrict__ A,
                                                const float* __restrict__ Bm,
                                                float* __restrict__ C,
                                                int M, int N, int K) {
  __shared__ float As[16][68];  // [k][m]
  __shared__ float Bs[16][68];  // [k][n]
  const int tid = threadIdx.x;
  const int tx = tid & 15, ty = tid >> 4;
  const int m0 = blockIdx.y * 64, n0 = blockIdx.x * 64;
  const int am = tid >> 2, ak = (tid & 3) * 4;   // A stage: 4 consecutive k / thread
  const int bk = tid >> 4, bn = (tid & 15) * 4;  // B stage: float4 along n

  float acc[4][4] = {};
  for (int k0 = 0; k0 < K; k0 += 16) {
    float4 a4 = *(const float4*)(A + (size_t)(m0 + am) * K + (k0 + ak));
    As[ak + 0][am] = a4.x;
    As[ak + 1][am] = a4.y;
    As[ak + 2][am] = a4.z;
    As[ak + 3][am] = a4.w;
    *(float4*)&Bs[bk][bn] = *(const float4*)(Bm + (size_t)(k0 + bk) * N + (n0 + bn));
    __syncthreads();
#pragma unroll
    for (int kk = 0; kk < 16; ++kk) {
      float4 av = *(const float4*)&As[kk][ty * 4];
      float4 bv = *(const float4*)&Bs[kk][tx * 4];
      const float a[4] = {av.x, av.y, av.z, av.w};
      const float bb[4] = {bv.x, bv.y, bv.z, bv.w};
#pragma unroll
      for (int i = 0; i < 4; ++i)
#pragma unroll
        for (int j = 0; j < 4; ++j) acc[i][j] = fmaf(a[i], bb[j], acc[i][j]);
    }
    __syncthreads();
  }
#pragma unroll
  for (int i = 0; i < 4; ++i) {
    float4 v = {acc[i][0], acc[i][1], acc[i][2], acc[i][3]};
    *(float4*)(C + (size_t)(m0 + ty * 4 + i) * N + (n0 + tx * 4)) = v;
  }
}

// ---------------------------------------------------------------------------
// RoPE + element-wise repeat + (B,S,*) -> (B,H,S,D) layout.
// One thread per (b,s,h,pair p). K/V head h dim d draws xk0[h*32 + d/2]
// (jnp.repeat along last axis BEFORE head reshape).
// ---------------------------------------------------------------------------
__global__ __launch_bounds__(256) void rope_layout(const float* __restrict__ xq,
                                                   const float* __restrict__ xk0,
                                                   const float* __restrict__ xv0,
                                                   float* __restrict__ Qr,
                                                   float* __restrict__ Kr,
                                                   float* __restrict__ Vr) {
  const int idx = blockIdx.x * blockDim.x + threadIdx.x;  // B*S*H*32 = 2^21
  if (idx >= NB * S_LEN * NH * 32) return;
  const int p = idx & 31;
  const int h = (idx >> 5) & (NH - 1);
  const int s = (idx >> 9) & (S_LEN - 1);
  const int b = idx >> 20;

  const float theta = c_thetas[p];
  const float ang = (float)(s + 1) * theta;
  float sn, cs;
  sincosf(ang, &sn, &cs);

  const size_t bs = (size_t)b * S_LEN + s;
  const size_t outBase = (((size_t)b * NH + h) * S_LEN + s) * DH + 2 * p;

  // Q: direct head split, rope on (even,odd) pair
  {
    const float xe = xq[bs * 1024 + h * 64 + 2 * p];
    const float xo = xq[bs * 1024 + h * 64 + 2 * p + 1];
    float2 r = {xe * cs - xo * sn, xe * sn + xo * cs};
    *(float2*)(Qr + outBase) = r;
  }
  // K: element-repeat then rope; pair members are equal
  {
    const float v = xk0[bs * 512 + h * 32 + p];
    float2 r = {v * cs - v * sn, v * sn + v * cs};
    *(float2*)(Kr + outBase) = r;
  }
  // V: element-repeat, no rope
  {
    const float w = xv0[bs * 512 + h * 32 + p];
    float2 r = {w, w};
    *(float2*)(Vr + outBase) = r;
  }
}

// ---------------------------------------------------------------------------
// Flash-style fused attention, fp32. Block = 256 threads = one (b,h, 64-query
// tile). Keys in tiles of 64. Thread (tx,ty): rows q0..q0+3 (q0=4*ty),
// cols {tx,tx+16,tx+32,tx+48} (stride-16 keeps LDS reads <=2-way).
// P is stored back into the K LDS buffer (saves 17 KB -> 52 KB total LDS).
// Output written directly in (B,S,H*D) layout for the final GEMM.
// ---------------------------------------------------------------------------
__global__ __launch_bounds__(256) void flash_attn(const float* __restrict__ Qr,
                                                  const float* __restrict__ Kr,
                                                  const float* __restrict__ Vr,
                                                  const float* __restrict__ mask,
                                                  float* __restrict__ O) {
  __shared__ float Qs[64][68];
  __shared__ float Ks[64][68];  // reused to hold P after scores are consumed
  __shared__ float Vs[64][68];
  const int tid = threadIdx.x;
  const int tx = tid & 15, ty = tid >> 4;
  const int q0 = ty * 4;
  const int s0 = blockIdx.x * 64;
  const int bh = blockIdx.y;  // b*16 + h
  const int b = bh >> 4, h = bh & 15;

  // stage Q tile (contiguous 16 KB)
  const float* Qp = Qr + ((size_t)bh * S_LEN + s0) * DH;
#pragma unroll
  for (int it = 0; it < 4; ++it) {
    int g = it * 1024 + tid * 4;
    *(float4*)&Qs[g >> 6][g & 63] = *(const float4*)(Qp + g);
  }

  float m_prev[4], l[4], o[4][4];
#pragma unroll
  for (int i = 0; i < 4; ++i) {
    m_prev[i] = -1e30f;
    l[i] = 0.f;
#pragma unroll
    for (int j = 0; j < 4; ++j) o[i][j] = 0.f;
  }

  for (int kt = 0; kt < S_LEN / 64; ++kt) {
    __syncthreads();  // prev tile's LDS reads done (also publishes Qs on kt=0)
    const float* Kp = Kr + ((size_t)bh * S_LEN + kt * 64) * DH;
    const float* Vp = Vr + ((size_t)bh * S_LEN + kt * 64) * DH;
#pragma unroll
    for (int it = 0; it < 4; ++it) {
      int g = it * 1024 + tid * 4;
      *(float4*)&Ks[g >> 6][g & 63] = *(const float4*)(Kp + g);
      *(float4*)&Vs[g >> 6][g & 63] = *(const float4*)(Vp + g);
    }
    __syncthreads();

    // S = Q @ K^T (64x64, k-dim = DH = 64)
    float sa[4][4] = {};
#pragma unroll
    for (int k4 = 0; k4 < 16; ++k4) {
      float4 aq[4], bq[4];
#pragma unroll
      for (int i = 0; i < 4; ++i) aq[i] = *(const float4*)&Qs[q0 + i][k4 * 4];
#pragma unroll
      for (int j = 0; j < 4; ++j) bq[j] = *(const float4*)&Ks[tx + 16 * j][k4 * 4];
#pragma unroll
      for (int i = 0; i < 4; ++i)
#pragma unroll
        for (int j = 0; j < 4; ++j)
          sa[i][j] += aq[i].x * bq[j].x + aq[i].y * bq[j].y +
                      aq[i].z * bq[j].z + aq[i].w * bq[j].w;
    }

    // scale + mask bias + online softmax
#pragma unroll
    for (int i = 0; i < 4; ++i) {
      const float* mrow =
          mask + ((size_t)b * S_LEN + (s0 + q0 + i)) * S_LEN + kt * 64;
      float mx = -1e30f;
#pragma unroll
      for (int j = 0; j < 4; ++j) {
        float mv = mrow[tx + 16 * j];
        float sc = sa[i][j] * 0.5f - (1.0f / mv - 1.0f);
        sa[i][j] = sc;
        mx = fmaxf(mx, sc);
      }
      mx = fmaxf(mx, __shfl_xor(mx, 1, 16));
      mx = fmaxf(mx, __shfl_xor(mx, 2, 16));
      mx = fmaxf(mx, __shfl_xor(mx, 4, 16));
      mx = fmaxf(mx, __shfl_xor(mx, 8, 16));
      const float mnew = fmaxf(m_prev[i], mx);
      const float alpha = __expf(m_prev[i] - mnew);
      m_prev[i] = mnew;
      float rs = 0.f;
#pragma unroll
      for (int j = 0; j < 4; ++j) {
        float pv = __expf(sa[i][j] - mnew);
        sa[i][j] = pv;
        rs += pv;
      }
      rs += __shfl_xor(rs, 1, 16);
      rs += __shfl_xor(rs, 2, 16);
      rs += __shfl_xor(rs, 4, 16);
      rs += __shfl_xor(rs, 8, 16);
      l[i] = l[i] * alpha + rs;
#pragma unroll
      for (int j = 0; j < 4; ++j) o[i][j] *= alpha;
    }

    __syncthreads();  // everyone done reading Ks as scores input
    // store P into the K buffer
#pragma unroll
    for (int i = 0; i < 4; ++i)
#pragma unroll
      for (int j = 0; j < 4; ++j) Ks[q0 + i][tx + 16 * j] = sa[i][j];
    __syncthreads();

    // O += P @ V
#pragma unroll
    for (int k4 = 0; k4 < 16; ++k4) {
      float4 pq[4];
#pragma unroll
      for (int i = 0; i < 4; ++i) pq[i] = *(const float4*)&Ks[q0 + i][k4 * 4];
#pragma unroll
      for (int kk = 0; kk < 4; ++kk) {
        float vv[4];
#pragma unroll
        for (int j = 0; j < 4; ++j) vv[j] = Vs[k4 * 4 + kk][tx + 16 * j];
#pragma unroll
        for (int i = 0; i < 4; ++i) {
          const float pv = ((const float*)&pq[i])[kk];
#pragma unroll
          for (int j = 0; j < 4; ++j) o[i][j] = fmaf(pv, vv[j], o[i][j]);
        }
      }
    }
  }

  // epilogue: normalize and write in (B,S,H*D) layout
#pragma unroll
  for (int i = 0; i < 4; ++i) {
    const float inv = 1.0f / l[i];
    float* Op = O + ((size_t)b * S_LEN + (s0 + q0 + i)) * (NH * DH) + h * DH;
#pragma unroll
    for (int j = 0; j < 4; ++j) Op[tx + 16 * j] = o[i][j] * inv;
  }
}

// ---------------------------------------------------------------------------
extern "C" void kernel_launch(void* const* d_in, const int* in_sizes, int n_in,
                              void* d_out, int out_size, void* d_ws, size_t ws_size,
                              hipStream_t stream) {
  const float* q    = (const float*)d_in[0];  // (2,2048,1024)
  const float* mask = (const float*)d_in[1];  // (2,1,2048,2048)
  const float* Wq   = (const float*)d_in[2];  // (1024,1024)
  const float* Wk   = (const float*)d_in[3];  // (1024,512)
  const float* Wv   = (const float*)d_in[4];  // (1024,512)
  const float* Wo   = (const float*)d_in[5];  // (1024,1024)
  float* out = (float*)d_out;                 // (2,2048,1024)
  float* ws = (float*)d_ws;

  const size_t M = (size_t)NB * S_LEN;  // 4096
  float* xq  = ws;                 // 4096*1024
  float* xk0 = xq + M * 1024;      // 4096*512
  float* xv0 = xk0 + M * 512;      // 4096*512
  float* Qr  = xv0 + M * 512;      // (B,H,S,D)
  float* Kr  = Qr + M * 1024;
  float* Vr  = Kr + M * 1024;
  float* O   = ws;                 // reuse xq region (dead after rope_layout)

  dim3 blk(256);
  // QKV projections
  gemm_f32<<<dim3(1024 / 64, M / 64), blk, 0, stream>>>(q, Wq, xq, M, 1024, 1024);
  gemm_f32<<<dim3(512 / 64, M / 64), blk, 0, stream>>>(q, Wk, xk0, M, 512, 1024);
  gemm_f32<<<dim3(512 / 64, M / 64), blk, 0, stream>>>(q, Wv, xv0, M, 512, 1024);
  // rope + repeat + transpose to (B,H,S,D)
  rope_layout<<<(NB * S_LEN * NH * 32) / 256, blk, 0, stream>>>(xq, xk0, xv0, Qr, Kr, Vr);
  // fused attention -> O in (B,S,H*D)
  flash_attn<<<dim3(S_LEN / 64, NB * NH), blk, 0, stream>>>(Qr, Kr, Vr, mask, O);
  // output projection
  gemm_f32<<<dim3(1024 / 64, M / 64), blk, 0, stream>>>(O, Wo, out, M, 1024, 1024);
}

// Round 2
// 368.192 us; speedup vs baseline: 3.6634x; 3.6634x over previous
//
#include <hip/hip_runtime.h>
#include <math.h>

#define S_LEN 2048
#define NB 2
#define NH 16
#define DH 64

typedef unsigned short u16;
typedef unsigned int u32;
typedef __attribute__((ext_vector_type(8))) short bf16x8;
typedef __attribute__((ext_vector_type(4))) float f32x4;

__device__ __forceinline__ u16 f2b(float f) {
  u32 u = __float_as_uint(f);
  u += 0x7fffu + ((u >> 16) & 1u);  // round-to-nearest-even
  return (u16)(u >> 16);
}
__device__ __forceinline__ float b2f(u16 u) { return __uint_as_float(((u32)u) << 16); }

// ---------------------------------------------------------------------------
// fp32 -> bf16 flat cast (n divisible by 4*256)
// ---------------------------------------------------------------------------
__global__ __launch_bounds__(256) void cast_bf16(const float* __restrict__ in,
                                                 u16* __restrict__ out, int n) {
  int i = (blockIdx.x * 256 + threadIdx.x) * 4;
  if (i < n) {
    float4 v = *(const float4*)(in + i);
    ushort4 o = {f2b(v.x), f2b(v.y), f2b(v.z), f2b(v.w)};
    *(ushort4*)(out + i) = o;
  }
}

// ---------------------------------------------------------------------------
// W (K x N, f32) -> WT (N x K, bf16). 32x32 LDS tile.
// ---------------------------------------------------------------------------
__global__ __launch_bounds__(256) void transpose_cast(const float* __restrict__ W,
                                                      u16* __restrict__ WT,
                                                      int K, int N) {
  __shared__ float t[32][33];
  const int tx = threadIdx.x & 31, ty = threadIdx.x >> 5;
  const int n0 = blockIdx.x * 32, k0 = blockIdx.y * 32;
#pragma unroll
  for (int i = 0; i < 4; ++i) {
    int k = k0 + ty + i * 8;
    t[ty + i * 8][tx] = W[(size_t)k * N + n0 + tx];
  }
  __syncthreads();
#pragma unroll
  for (int i = 0; i < 4; ++i) {
    int nr = n0 + ty + i * 8;
    WT[(size_t)nr * K + k0 + tx] = f2b(t[tx][ty + i * 8]);
  }
}

// ---------------------------------------------------------------------------
// biasT[b][key][q] = bf16(1 - 1/mask[b][q][key])   (additive softmax bias)
// ---------------------------------------------------------------------------
__global__ __launch_bounds__(256) void bias_transpose(const float* __restrict__ mask,
                                                      u16* __restrict__ biasT) {
  __shared__ float t[32][33];
  const int tx = threadIdx.x & 31, ty = threadIdx.x >> 5;
  const int k0 = blockIdx.x * 32, q0 = blockIdx.y * 32;
  const size_t base = (size_t)blockIdx.z * S_LEN * S_LEN;
#pragma unroll
  for (int i = 0; i < 4; ++i) {
    int q = q0 + ty + i * 8;
    t[ty + i * 8][tx] = 1.0f - 1.0f / mask[base + (size_t)q * S_LEN + k0 + tx];
  }
  __syncthreads();
#pragma unroll
  for (int i = 0; i < 4; ++i) {
    int key = k0 + ty + i * 8;
    biasT[base + (size_t)key * S_LEN + q0 + tx] = f2b(t[tx][ty + i * 8]);
  }
}

// ---------------------------------------------------------------------------
// bf16 MFMA GEMM: C[M,N] = A(M,K) @ Bt(N,K)^T. 128x128 tile, BK=32,
// 256 threads / 4 waves, each wave 64x64 (4x4 frags of 16x16x32).
// LDS rows padded to 40 bf16 (80 B): frag ds_read_b128 <=2-way conflicts.
// ---------------------------------------------------------------------------
template <int BF16OUT>
__global__ __launch_bounds__(256) void gemm_bt(const u16* __restrict__ A,
                                               const u16* __restrict__ Bt,
                                               void* __restrict__ Cv,
                                               int M, int N, int K) {
  __shared__ __align__(16) u16 As[128 * 40];
  __shared__ __align__(16) u16 Bs[128 * 40];
  const int tid = threadIdx.x;
  const int w = tid >> 6, lane = tid & 63, lg = lane >> 4, ln = lane & 15;
  const int m0 = blockIdx.y * 128, n0 = blockIdx.x * 128;
  const int wm = (w & 1) * 64, wn = (w >> 1) * 64;

  f32x4 acc[4][4];
#pragma unroll
  for (int i = 0; i < 4; ++i)
#pragma unroll
    for (int j = 0; j < 4; ++j) acc[i][j] = (f32x4)0.0f;

  const int r0 = tid >> 2, c0 = tid & 3;        // chunk 0
  const int r1 = (tid + 256) >> 2, c1 = tid & 3;  // chunk 1

  for (int k0 = 0; k0 < K; k0 += 32) {
    __syncthreads();
    *(uint4*)&As[r0 * 40 + c0 * 8] = *(const uint4*)(A + (size_t)(m0 + r0) * K + k0 + c0 * 8);
    *(uint4*)&Bs[r0 * 40 + c0 * 8] = *(const uint4*)(Bt + (size_t)(n0 + r0) * K + k0 + c0 * 8);
    *(uint4*)&As[r1 * 40 + c1 * 8] = *(const uint4*)(A + (size_t)(m0 + r1) * K + k0 + c1 * 8);
    *(uint4*)&Bs[r1 * 40 + c1 * 8] = *(const uint4*)(Bt + (size_t)(n0 + r1) * K + k0 + c1 * 8);
    __syncthreads();

    bf16x8 af[4], bfr[4];
#pragma unroll
    for (int mt = 0; mt < 4; ++mt)
      af[mt] = *(const bf16x8*)&As[(wm + mt * 16 + ln) * 40 + lg * 8];
#pragma unroll
    for (int nt = 0; nt < 4; ++nt)
      bfr[nt] = *(const bf16x8*)&Bs[(wn + nt * 16 + ln) * 40 + lg * 8];
#pragma unroll
    for (int mt = 0; mt < 4; ++mt)
#pragma unroll
      for (int nt = 0; nt < 4; ++nt)
        acc[mt][nt] = __builtin_amdgcn_mfma_f32_16x16x32_bf16(af[mt], bfr[nt], acc[mt][nt], 0, 0, 0);
  }

#pragma unroll
  for (int mt = 0; mt < 4; ++mt)
#pragma unroll
    for (int nt = 0; nt < 4; ++nt)
#pragma unroll
      for (int r = 0; r < 4; ++r) {
        int row = m0 + wm + mt * 16 + lg * 4 + r;
        int col = n0 + wn + nt * 16 + ln;
        if (BF16OUT)
          ((u16*)Cv)[(size_t)row * N + col] = f2b(acc[mt][nt][r]);
        else
          ((float*)Cv)[(size_t)row * N + col] = acc[mt][nt][r];
      }
}

// ---------------------------------------------------------------------------
// RoPE for Q and K (bf16 in/out). K uses element-wise repeat: source dim
// h*32+p feeds output pair (2p, 2p+1). Writes (B,H,S,D).
// ---------------------------------------------------------------------------
__global__ __launch_bounds__(256) void rope_qk(const u16* __restrict__ xq,
                                               const u16* __restrict__ xk,
                                               u16* __restrict__ Qr,
                                               u16* __restrict__ Kr) {
  const int idx = blockIdx.x * 256 + threadIdx.x;  // 2^21
  const int p = idx & 31;
  const int h = (idx >> 5) & (NH - 1);
  const int s = (idx >> 9) & (S_LEN - 1);
  const int b = idx >> 20;

  // theta = 10^-p in fp32
  float theta = __powf(10.0f, -(float)p);
  // exact table-free alternative is fine; but match fp32 10**-p closely:
  // __powf error ~1ulp at these points; RoPE angles tolerate it at bf16 output.
  float ang = (float)(s + 1) * theta;
  float sn, cs;
  sincosf(ang, &sn, &cs);

  const size_t bs = (size_t)b * S_LEN + s;
  const size_t outBase = (((size_t)b * NH + h) * S_LEN + s) * DH + 2 * p;

  {
    u32 qv = *(const u32*)(xq + bs * 1024 + h * 64 + 2 * p);
    float xe = b2f((u16)(qv & 0xffffu)), xo = b2f((u16)(qv >> 16));
    u32 o = (u32)f2b(xe * cs - xo * sn) | ((u32)f2b(xe * sn + xo * cs) << 16);
    *(u32*)(Qr + outBase) = o;
  }
  {
    float v = b2f(xk[bs * 512 + h * 32 + p]);
    u32 o = (u32)f2b(v * cs - v * sn) | ((u32)f2b(v * sn + v * cs) << 16);
    *(u32*)(Kr + outBase) = o;
  }
}

// ---------------------------------------------------------------------------
// MFMA flash attention. Block = 256 thr (4 waves), Q-tile 128, K-tile 64.
// Wave w owns q rows [w*32, w*32+32) (mt in {0,1}).
// S = Q K^T: A-frag = Q rows, B-frag = K rows (identical read pattern).
// C-layout: row=(lg*4+reg), col=ln. P -> LDS (bf16) -> A-frags for PV.
// V comes from xvT (dim-major) so B-frags are contiguous ds_read_b128.
// ---------------------------------------------------------------------------
__global__ __launch_bounds__(256) void flash_mfma(const u16* __restrict__ Qr,
                                                  const u16* __restrict__ Kr,
                                                  const u16* __restrict__ xvT,
                                                  const u16* __restrict__ biasT,
                                                  u16* __restrict__ O) {
  __shared__ __align__(16) u16 Qs[128 * 72];
  __shared__ __align__(16) u16 Ks[64 * 72];
  __shared__ __align__(16) u16 Vt[64 * 72];
  __shared__ __align__(16) u16 Ps[128 * 72];

  const int tid = threadIdx.x;
  const int w = tid >> 6, lane = tid & 63, lg = lane >> 4, ln = lane & 15;
  const int bh = blockIdx.x, b = bh >> 4, h = bh & 15;
  const int q0 = blockIdx.y * 128;
  const int wq = w * 32;

  // stage Q (128 x 64)
  {
    const u16* Qg = Qr + ((size_t)bh * S_LEN + q0) * DH;
#pragma unroll
    for (int i = 0; i < 4; ++i) {
      int c = tid + 256 * i, r = c >> 3, ch = c & 7;
      *(uint4*)&Qs[r * 72 + ch * 8] = *(const uint4*)(Qg + r * 64 + ch * 8);
    }
  }
  __syncthreads();

  bf16x8 aq[2][2];
#pragma unroll
  for (int mt = 0; mt < 2; ++mt)
#pragma unroll
    for (int kh = 0; kh < 2; ++kh)
      aq[mt][kh] = *(const bf16x8*)&Qs[(wq + mt * 16 + ln) * 72 + kh * 32 + lg * 8];

  float m_i[2][4], l_i[2][4];
  f32x4 o[2][4];
#pragma unroll
  for (int mt = 0; mt < 2; ++mt) {
#pragma unroll
    for (int r = 0; r < 4; ++r) { m_i[mt][r] = -1e30f; l_i[mt][r] = 0.0f; }
#pragma unroll
    for (int dt = 0; dt < 4; ++dt) o[mt][dt] = (f32x4)0.0f;
  }

  const u16* Kg = Kr + (size_t)bh * S_LEN * DH;
  const u16* Vg = xvT + (size_t)(h * 32) * (NB * S_LEN) + (size_t)b * S_LEN;
  const u16* Bg = biasT + (size_t)b * S_LEN * S_LEN;

  for (int kt = 0; kt < S_LEN / 64; ++kt) {
    __syncthreads();  // prev iter's Ks/Vt/Ps reads complete

    // bias loads (4 consecutive q per lane = one ushort4)
    ushort4 braw[2][4];
#pragma unroll
    for (int mt = 0; mt < 2; ++mt)
#pragma unroll
      for (int ct = 0; ct < 4; ++ct) {
        int key = kt * 64 + ct * 16 + ln;
        int qg = q0 + wq + mt * 16 + lg * 4;
        braw[mt][ct] = *(const ushort4*)(Bg + (size_t)key * S_LEN + qg);
      }

    // stage K (64 x 64)
#pragma unroll
    for (int i = 0; i < 2; ++i) {
      int c = tid + 256 * i, r = c >> 3, ch = c & 7;
      *(uint4*)&Ks[r * 72 + ch * 8] = *(const uint4*)(Kg + (size_t)(kt * 64 + r) * 64 + ch * 8);
    }
    // stage V^T with element-repeat duplication (rows 2e, 2e+1)
    {
      int e = tid >> 3, ch = tid & 7;
      uint4 v = *(const uint4*)(Vg + (size_t)e * (NB * S_LEN) + kt * 64 + ch * 8);
      *(uint4*)&Vt[(2 * e) * 72 + ch * 8] = v;
      *(uint4*)&Vt[(2 * e + 1) * 72 + ch * 8] = v;
    }
    __syncthreads();

    // S = Q K^T
    bf16x8 bk[4][2];
#pragma unroll
    for (int ct = 0; ct < 4; ++ct)
#pragma unroll
      for (int kh = 0; kh < 2; ++kh)
        bk[ct][kh] = *(const bf16x8*)&Ks[(ct * 16 + ln) * 72 + kh * 32 + lg * 8];

    f32x4 sa[2][4];
#pragma unroll
    for (int mt = 0; mt < 2; ++mt)
#pragma unroll
      for (int ct = 0; ct < 4; ++ct) {
        f32x4 z = (f32x4)0.0f;
        z = __builtin_amdgcn_mfma_f32_16x16x32_bf16(aq[mt][0], bk[ct][0], z, 0, 0, 0);
        sa[mt][ct] = __builtin_amdgcn_mfma_f32_16x16x32_bf16(aq[mt][1], bk[ct][1], z, 0, 0, 0);
      }

    // online softmax (per q-row = per (lg, reg))
#pragma unroll
    for (int mt = 0; mt < 2; ++mt) {
      float al[4];
#pragma unroll
      for (int r = 0; r < 4; ++r) {
        float sb[4];
        float mx = -1e30f;
#pragma unroll
        for (int ct = 0; ct < 4; ++ct) {
          float nb = b2f(((const u16*)&braw[mt][ct])[r]);
          sb[ct] = sa[mt][ct][r] * 0.5f + nb;
          mx = fmaxf(mx, sb[ct]);
        }
        mx = fmaxf(mx, __shfl_xor(mx, 1));
        mx = fmaxf(mx, __shfl_xor(mx, 2));
        mx = fmaxf(mx, __shfl_xor(mx, 4));
        mx = fmaxf(mx, __shfl_xor(mx, 8));
        float mn = fmaxf(m_i[mt][r], mx);
        al[r] = __expf(m_i[mt][r] - mn);
        m_i[mt][r] = mn;
        float rs = 0.0f;
#pragma unroll
        for (int ct = 0; ct < 4; ++ct) {
          float p = __expf(sb[ct] - mn);
          rs += p;
          Ps[(wq + mt * 16 + lg * 4 + r) * 72 + ct * 16 + ln] = f2b(p);
        }
        rs += __shfl_xor(rs, 1);
        rs += __shfl_xor(rs, 2);
        rs += __shfl_xor(rs, 4);
        rs += __shfl_xor(rs, 8);
        l_i[mt][r] = l_i[mt][r] * al[r] + rs;
      }
#pragma unroll
      for (int dt = 0; dt < 4; ++dt)
#pragma unroll
        for (int r = 0; r < 4; ++r) o[mt][dt][r] *= al[r];
    }
    __syncthreads();  // Ps published

    // O += P V
    bf16x8 ap[2][2], bv[4][2];
#pragma unroll
    for (int mt = 0; mt < 2; ++mt)
#pragma unroll
      for (int kh = 0; kh < 2; ++kh)
        ap[mt][kh] = *(const bf16x8*)&Ps[(wq + mt * 16 + ln) * 72 + kh * 32 + lg * 8];
#pragma unroll
    for (int dt = 0; dt < 4; ++dt)
#pragma unroll
      for (int kh = 0; kh < 2; ++kh)
        bv[dt][kh] = *(const bf16x8*)&Vt[(dt * 16 + ln) * 72 + kh * 32 + lg * 8];
#pragma unroll
    for (int mt = 0; mt < 2; ++mt)
#pragma unroll
      for (int dt = 0; dt < 4; ++dt) {
        o[mt][dt] = __builtin_amdgcn_mfma_f32_16x16x32_bf16(ap[mt][0], bv[dt][0], o[mt][dt], 0, 0, 0);
        o[mt][dt] = __builtin_amdgcn_mfma_f32_16x16x32_bf16(ap[mt][1], bv[dt][1], o[mt][dt], 0, 0, 0);
      }
  }

  // epilogue: normalize, write (B,S,H*D) bf16
#pragma unroll
  for (int mt = 0; mt < 2; ++mt)
#pragma unroll
    for (int r = 0; r < 4; ++r) {
      float inv = 1.0f / l_i[mt][r];
      int srow = q0 + wq + mt * 16 + lg * 4 + r;
#pragma unroll
      for (int dt = 0; dt < 4; ++dt) {
        O[((size_t)b * S_LEN + srow) * (NH * DH) + h * DH + dt * 16 + ln] =
            f2b(o[mt][dt][r] * inv);
      }
    }
}

// ---------------------------------------------------------------------------
extern "C" void kernel_launch(void* const* d_in, const int* in_sizes, int n_in,
                              void* d_out, int out_size, void* d_ws, size_t ws_size,
                              hipStream_t stream) {
  const float* q    = (const float*)d_in[0];
  const float* mask = (const float*)d_in[1];
  const float* Wq   = (const float*)d_in[2];
  const float* Wk   = (const float*)d_in[3];
  const float* Wv   = (const float*)d_in[4];
  const float* Wo   = (const float*)d_in[5];
  float* out = (float*)d_out;

  const size_t M = (size_t)NB * S_LEN;  // 4096
  u16* p = (u16*)d_ws;
  u16* qb    = p; p += M * 1024;          // 4096x1024
  u16* WqT   = p; p += 1024 * 1024;       // (N=1024, K=1024)
  u16* WkT   = p; p += 512 * 1024;
  u16* WvT   = p; p += 512 * 1024;
  u16* WoT   = p; p += 1024 * 1024;
  u16* biasT = p; p += (size_t)NB * S_LEN * S_LEN;  // bf16 (b, key, q)
  u16* xq    = p; p += M * 1024;
  u16* xk0   = p; p += M * 512;
  u16* xvT   = p; p += 512 * M;           // (512, B*S)
  u16* Qr    = p; p += M * 1024;          // (B,H,S,D)
  u16* Kr    = p; p += M * 1024;
  u16* Oc    = p; p += M * 1024;          // attention out, (B,S,1024) bf16

  dim3 blk(256);
  // prep
  cast_bf16<<<(M * 1024) / 1024, blk, 0, stream>>>(q, qb, (int)(M * 1024));
  transpose_cast<<<dim3(1024 / 32, 1024 / 32), blk, 0, stream>>>(Wq, WqT, 1024, 1024);
  transpose_cast<<<dim3(512 / 32, 1024 / 32), blk, 0, stream>>>(Wk, WkT, 1024, 512);
  transpose_cast<<<dim3(512 / 32, 1024 / 32), blk, 0, stream>>>(Wv, WvT, 1024, 512);
  transpose_cast<<<dim3(1024 / 32, 1024 / 32), blk, 0, stream>>>(Wo, WoT, 1024, 1024);
  bias_transpose<<<dim3(S_LEN / 32, S_LEN / 32, NB), blk, 0, stream>>>(mask, biasT);

  // projections (bf16 MFMA)
  gemm_bt<1><<<dim3(1024 / 128, M / 128), blk, 0, stream>>>(qb, WqT, xq, M, 1024, 1024);
  gemm_bt<1><<<dim3(512 / 128, M / 128), blk, 0, stream>>>(qb, WkT, xk0, M, 512, 1024);
  // xvT = Wv^T @ q^T  (same kernel, swapped roles) -> (512, B*S) dim-major
  gemm_bt<1><<<dim3(M / 128, 512 / 128), blk, 0, stream>>>(WvT, qb, xvT, 512, M, 1024);

  // rope Q,K -> (B,H,S,D)
  rope_qk<<<(NB * S_LEN * NH * 32) / 256, blk, 0, stream>>>(xq, xk0, Qr, Kr);

  // fused attention
  flash_mfma<<<dim3(NB * NH, S_LEN / 128), blk, 0, stream>>>(Qr, Kr, xvT, biasT, Oc);

  // output projection (fp32 out)
  gemm_bt<0><<<dim3(1024 / 128, M / 128), blk, 0, stream>>>(Oc, WoT, out, M, 1024, 1024);
}

// Round 3
// 311.416 us; speedup vs baseline: 4.3313x; 1.1823x over previous
//
#include <hip/hip_runtime.h>
#include <math.h>

#define S_LEN 2048
#define NB 2
#define NH 16
#define DH 64

typedef unsigned short u16;
typedef unsigned int u32;
typedef __attribute__((ext_vector_type(8))) short bf16x8;
typedef __attribute__((ext_vector_type(4))) float f32x4;

__device__ __forceinline__ u16 f2b(float f) {
  u32 u = __float_as_uint(f);
  u += 0x7fffu + ((u >> 16) & 1u);  // round-to-nearest-even
  return (u16)(u >> 16);
}
__device__ __forceinline__ float b2f(u16 u) { return __uint_as_float(((u32)u) << 16); }
// pack two f32 -> two bf16 (round-to-nearest-away; ties ~never occur for exp outputs)
__device__ __forceinline__ u32 packbf(float a, float b) {
  u32 ua = __float_as_uint(a) + 0x8000u;
  u32 ub = __float_as_uint(b) + 0x8000u;
  return (ua >> 16) | (ub & 0xffff0000u);
}

// ---------------------------------------------------------------------------
// fp32 -> bf16 flat cast
// ---------------------------------------------------------------------------
__global__ __launch_bounds__(256) void cast_bf16(const float* __restrict__ in,
                                                 u16* __restrict__ out, int n) {
  int i = (blockIdx.x * 256 + threadIdx.x) * 4;
  if (i < n) {
    float4 v = *(const float4*)(in + i);
    ushort4 o = {f2b(v.x), f2b(v.y), f2b(v.z), f2b(v.w)};
    *(ushort4*)(out + i) = o;
  }
}

// ---------------------------------------------------------------------------
// W (K x N, f32) -> WT (N x K, bf16). 32x32 LDS tile.
// ---------------------------------------------------------------------------
__global__ __launch_bounds__(256) void transpose_cast(const float* __restrict__ W,
                                                      u16* __restrict__ WT,
                                                      int K, int N) {
  __shared__ float t[32][33];
  const int tx = threadIdx.x & 31, ty = threadIdx.x >> 5;
  const int n0 = blockIdx.x * 32, k0 = blockIdx.y * 32;
#pragma unroll
  for (int i = 0; i < 4; ++i) {
    int k = k0 + ty + i * 8;
    t[ty + i * 8][tx] = W[(size_t)k * N + n0 + tx];
  }
  __syncthreads();
#pragma unroll
  for (int i = 0; i < 4; ++i) {
    int nr = n0 + ty + i * 8;
    WT[(size_t)nr * K + k0 + tx] = f2b(t[tx][ty + i * 8]);
  }
}

// ---------------------------------------------------------------------------
// bias[b][q][key] = bf16(1 - 1/mask)  (elementwise, no transpose)
// ---------------------------------------------------------------------------
__global__ __launch_bounds__(256) void bias_prep(const float* __restrict__ mask,
                                                 u16* __restrict__ bias, int n) {
  int i = (blockIdx.x * 256 + threadIdx.x) * 4;
  if (i < n) {
    float4 v = *(const float4*)(mask + i);
    ushort4 o = {f2b(1.0f - 1.0f / v.x), f2b(1.0f - 1.0f / v.y),
                 f2b(1.0f - 1.0f / v.z), f2b(1.0f - 1.0f / v.w)};
    *(ushort4*)(bias + i) = o;
  }
}

// ---------------------------------------------------------------------------
// bf16 MFMA GEMM: C[M,N] = A(M,K) @ Bt(N,K)^T. 128x128 tile, BK=32.
// (unchanged from R2 — known correct)
// ---------------------------------------------------------------------------
template <int BF16OUT>
__global__ __launch_bounds__(256) void gemm_bt(const u16* __restrict__ A,
                                               const u16* __restrict__ Bt,
                                               void* __restrict__ Cv,
                                               int M, int N, int K) {
  __shared__ __align__(16) u16 As[128 * 40];
  __shared__ __align__(16) u16 Bs[128 * 40];
  const int tid = threadIdx.x;
  const int w = tid >> 6, lane = tid & 63, lg = lane >> 4, ln = lane & 15;
  const int m0 = blockIdx.y * 128, n0 = blockIdx.x * 128;
  const int wm = (w & 1) * 64, wn = (w >> 1) * 64;

  f32x4 acc[4][4];
#pragma unroll
  for (int i = 0; i < 4; ++i)
#pragma unroll
    for (int j = 0; j < 4; ++j) acc[i][j] = (f32x4)0.0f;

  const int r0 = tid >> 2, c0 = tid & 3;
  const int r1 = (tid + 256) >> 2, c1 = tid & 3;

  for (int k0 = 0; k0 < K; k0 += 32) {
    __syncthreads();
    *(uint4*)&As[r0 * 40 + c0 * 8] = *(const uint4*)(A + (size_t)(m0 + r0) * K + k0 + c0 * 8);
    *(uint4*)&Bs[r0 * 40 + c0 * 8] = *(const uint4*)(Bt + (size_t)(n0 + r0) * K + k0 + c0 * 8);
    *(uint4*)&As[r1 * 40 + c1 * 8] = *(const uint4*)(A + (size_t)(m0 + r1) * K + k0 + c1 * 8);
    *(uint4*)&Bs[r1 * 40 + c1 * 8] = *(const uint4*)(Bt + (size_t)(n0 + r1) * K + k0 + c1 * 8);
    __syncthreads();

    bf16x8 af[4], bfr[4];
#pragma unroll
    for (int mt = 0; mt < 4; ++mt)
      af[mt] = *(const bf16x8*)&As[(wm + mt * 16 + ln) * 40 + lg * 8];
#pragma unroll
    for (int nt = 0; nt < 4; ++nt)
      bfr[nt] = *(const bf16x8*)&Bs[(wn + nt * 16 + ln) * 40 + lg * 8];
#pragma unroll
    for (int mt = 0; mt < 4; ++mt)
#pragma unroll
      for (int nt = 0; nt < 4; ++nt)
        acc[mt][nt] = __builtin_amdgcn_mfma_f32_16x16x32_bf16(af[mt], bfr[nt], acc[mt][nt], 0, 0, 0);
  }

#pragma unroll
  for (int mt = 0; mt < 4; ++mt)
#pragma unroll
    for (int nt = 0; nt < 4; ++nt)
#pragma unroll
      for (int r = 0; r < 4; ++r) {
        int row = m0 + wm + mt * 16 + lg * 4 + r;
        int col = n0 + wn + nt * 16 + ln;
        if (BF16OUT)
          ((u16*)Cv)[(size_t)row * N + col] = f2b(acc[mt][nt][r]);
        else
          ((float*)Cv)[(size_t)row * N + col] = acc[mt][nt][r];
      }
}

// ---------------------------------------------------------------------------
// RoPE for Q and K from the fused QK projection (row stride 1536).
// Q gets the 0.5 score scale folded in (exact power of two, single rounding).
// K uses element-wise repeat: source dim h*32+p -> output pair (2p, 2p+1).
// Writes (B,H,S,D) bf16.
// ---------------------------------------------------------------------------
__global__ __launch_bounds__(256) void rope_qk(const u16* __restrict__ xqk,
                                               u16* __restrict__ Qr,
                                               u16* __restrict__ Kr) {
  const int idx = blockIdx.x * 256 + threadIdx.x;  // 2^21
  const int p = idx & 31;
  const int h = (idx >> 5) & (NH - 1);
  const int s = (idx >> 9) & (S_LEN - 1);
  const int b = idx >> 20;

  float theta = __powf(10.0f, -(float)p);
  float ang = (float)(s + 1) * theta;
  float sn, cs;
  __sincosf(ang, &sn, &cs);

  const size_t bs = (size_t)b * S_LEN + s;
  const size_t rowBase = bs * 1536;
  const size_t outBase = (((size_t)b * NH + h) * S_LEN + s) * DH + 2 * p;

  {
    u32 qv = *(const u32*)(xqk + rowBase + h * 64 + 2 * p);
    float xe = b2f((u16)(qv & 0xffffu)), xo = b2f((u16)(qv >> 16));
    // fold score scale 0.5 into Q (exact)
    u32 o = (u32)f2b((xe * cs - xo * sn) * 0.5f) |
            ((u32)f2b((xe * sn + xo * cs) * 0.5f) << 16);
    *(u32*)(Qr + outBase) = o;
  }
  {
    float v = b2f(xqk[rowBase + 1024 + h * 32 + p]);
    u32 o = (u32)f2b(v * cs - v * sn) | ((u32)f2b(v * sn + v * cs) << 16);
    *(u32*)(Kr + outBase) = o;
  }
}

// ---------------------------------------------------------------------------
// MFMA flash attention, transposed-score orientation.
// Block = 256 thr (4 waves). Q-tile 128 (wave w owns q columns w*32..w*32+31),
// K-tile 64. S^T = K·Q^T: C-layout row=key(lg*4+reg), col=q(ln) — key
// reduction is in-lane + 2 shuffles. P is wave-private in LDS (reuses the Q
// staging buffer). PV computed as O^T = V^T·P^T (xvT is dim-major, repeat
// handled by duplicated row staging). All LDS tiles use unpadded rows of 8
// 16B-chunks with chunk ^= (row&7) XOR swizzle -> conflict-spread b128.
// ---------------------------------------------------------------------------
__global__ __launch_bounds__(256) void flash_mfma(const u16* __restrict__ Qr,
                                                  const u16* __restrict__ Kr,
                                                  const u16* __restrict__ xvT,
                                                  const u16* __restrict__ bias,
                                                  u16* __restrict__ O) {
  __shared__ __align__(16) u16 Ks[64 * 64];
  __shared__ __align__(16) u16 Vt[64 * 64];
  __shared__ __align__(16) u16 QP[128 * 64];  // Q staging, then per-wave P (4KB each)

  const int tid = threadIdx.x;
  const int w = tid >> 6, lane = tid & 63, lg = lane >> 4, ln = lane & 15;
  const int bh = blockIdx.x, b = bh >> 4, h = bh & 15;
  const int q0 = blockIdx.y * 128;
  const int wq = w * 32;
  const int sw = ln & 7;  // row-swizzle key for all frag reads (row ≡ ln mod 8)

  // ---- stage Q (128 x 64), swizzled ----
  {
    const u16* Qg = Qr + ((size_t)bh * S_LEN + q0) * DH;
#pragma unroll
    for (int i = 0; i < 4; ++i) {
      int idx = tid + 256 * i, r = idx >> 3, ch = idx & 7;
      *(uint4*)&QP[r * 64 + ((ch ^ (r & 7)) * 8)] = *(const uint4*)(Qg + r * 64 + ch * 8);
    }
  }
  __syncthreads();

  // ---- Q fragments (loop-invariant): B-operand of S^T, n=q ----
  bf16x8 aq[2][2];
#pragma unroll
  for (int qt = 0; qt < 2; ++qt)
#pragma unroll
    for (int kh = 0; kh < 2; ++kh)
      aq[qt][kh] = *(const bf16x8*)&QP[(wq + qt * 16 + ln) * 64 + (((kh * 4 + lg) ^ sw) * 8)];

  float m_i[2] = {-1e30f, -1e30f}, l_i[2] = {0.0f, 0.0f};
  f32x4 o[2][4];  // [qt][dt], O^T C-layout: row=d(lg*4+reg), col=q(ln)
#pragma unroll
  for (int qt = 0; qt < 2; ++qt)
#pragma unroll
    for (int dt = 0; dt < 4; ++dt) o[qt][dt] = (f32x4)0.0f;

  const u16* Kg = Kr + (size_t)bh * S_LEN * DH;
  const u16* Vg = xvT + (size_t)(h * 32) * (NB * S_LEN) + (size_t)b * S_LEN;
  const u16* Bg = bias + ((size_t)b * S_LEN + q0) * S_LEN;
  u16* Pw = &QP[w * 2048];  // wave-private P: 32 q-rows x 64 keys

  for (int kt = 0; kt < S_LEN / 64; ++kt) {
    // bias loads issued early (no LDS dependency)
    ushort4 braw[2][4];
#pragma unroll
    for (int qt = 0; qt < 2; ++qt)
#pragma unroll
      for (int kp = 0; kp < 4; ++kp)
        braw[qt][kp] = *(const ushort4*)(Bg + (size_t)(wq + qt * 16 + ln) * S_LEN +
                                         kt * 64 + kp * 16 + lg * 4);

    __syncthreads();  // prev iter's Ks/Vt reads complete
    // stage K (64 keys x 64 d), swizzled
#pragma unroll
    for (int i = 0; i < 2; ++i) {
      int idx = tid + 256 * i, r = idx >> 3, ch = idx & 7;
      *(uint4*)&Ks[r * 64 + ((ch ^ (r & 7)) * 8)] =
          *(const uint4*)(Kg + (size_t)(kt * 64 + r) * 64 + ch * 8);
    }
    // stage V^T (64 d x 64 keys) with element-repeat row duplication
    {
      int e = tid >> 3, ch = tid & 7;
      uint4 v = *(const uint4*)(Vg + (size_t)e * (NB * S_LEN) + kt * 64 + ch * 8);
      *(uint4*)&Vt[(2 * e) * 64 + ((ch ^ ((2 * e) & 7)) * 8)] = v;
      *(uint4*)&Vt[(2 * e + 1) * 64 + ((ch ^ ((2 * e + 1) & 7)) * 8)] = v;
    }
    __syncthreads();

    // ---- S^T = K · Q^T ----
    f32x4 sab[4][2];  // [key-tile][qt]
#pragma unroll
    for (int kp = 0; kp < 4; ++kp) {
      bf16x8 ak[2];
#pragma unroll
      for (int kh = 0; kh < 2; ++kh)
        ak[kh] = *(const bf16x8*)&Ks[(kp * 16 + ln) * 64 + (((kh * 4 + lg) ^ sw) * 8)];
#pragma unroll
      for (int qt = 0; qt < 2; ++qt) {
        f32x4 z = (f32x4)0.0f;
        z = __builtin_amdgcn_mfma_f32_16x16x32_bf16(ak[0], aq[qt][0], z, 0, 0, 0);
        sab[kp][qt] = __builtin_amdgcn_mfma_f32_16x16x32_bf16(ak[1], aq[qt][1], z, 0, 0, 0);
      }
    }

    // ---- online softmax (per q = per ln, per qt) ----
#pragma unroll
    for (int qt = 0; qt < 2; ++qt) {
      float mx = -1e30f;
#pragma unroll
      for (int kp = 0; kp < 4; ++kp) {
        const ushort4 bq = braw[qt][kp];
        sab[kp][qt][0] += b2f(bq.x);
        sab[kp][qt][1] += b2f(bq.y);
        sab[kp][qt][2] += b2f(bq.z);
        sab[kp][qt][3] += b2f(bq.w);
#pragma unroll
        for (int r = 0; r < 4; ++r) mx = fmaxf(mx, sab[kp][qt][r]);
      }
      mx = fmaxf(mx, __shfl_xor(mx, 16));
      mx = fmaxf(mx, __shfl_xor(mx, 32));
      const float mn = fmaxf(m_i[qt], mx);
      const float alpha = __expf(m_i[qt] - mn);
      m_i[qt] = mn;
      float rs = 0.0f;
#pragma unroll
      for (int kp = 0; kp < 4; ++kp) {
        float e0 = __expf(sab[kp][qt][0] - mn);
        float e1 = __expf(sab[kp][qt][1] - mn);
        float e2 = __expf(sab[kp][qt][2] - mn);
        float e3 = __expf(sab[kp][qt][3] - mn);
        rs += (e0 + e1) + (e2 + e3);
        // keys kp*16 + lg*4 + {0..3} at row qt*16+ln, swizzled chunk
        uint2 pp = {packbf(e0, e1), packbf(e2, e3)};
        *(uint2*)&Pw[(qt * 16 + ln) * 64 +
                     (((kp * 2 + (lg >> 1)) ^ sw) * 8) + (lg & 1) * 4] = pp;
      }
      rs += __shfl_xor(rs, 16);
      rs += __shfl_xor(rs, 32);
      l_i[qt] = l_i[qt] * alpha + rs;
#pragma unroll
      for (int dt = 0; dt < 4; ++dt) o[qt][dt] *= alpha;
    }
    // P is wave-private: no barrier needed (DS ops are in-order per wave)

    // ---- O^T += V^T · P^T ----
    bf16x8 bp[2][2];
#pragma unroll
    for (int qt = 0; qt < 2; ++qt)
#pragma unroll
      for (int kh = 0; kh < 2; ++kh)
        bp[qt][kh] = *(const bf16x8*)&Pw[(qt * 16 + ln) * 64 + (((kh * 4 + lg) ^ sw) * 8)];
#pragma unroll
    for (int dt = 0; dt < 4; ++dt) {
      bf16x8 av[2];
#pragma unroll
      for (int kh = 0; kh < 2; ++kh)
        av[kh] = *(const bf16x8*)&Vt[(dt * 16 + ln) * 64 + (((kh * 4 + lg) ^ sw) * 8)];
#pragma unroll
      for (int qt = 0; qt < 2; ++qt) {
        o[qt][dt] = __builtin_amdgcn_mfma_f32_16x16x32_bf16(av[0], bp[qt][0], o[qt][dt], 0, 0, 0);
        o[qt][dt] = __builtin_amdgcn_mfma_f32_16x16x32_bf16(av[1], bp[qt][1], o[qt][dt], 0, 0, 0);
      }
    }
  }

  // ---- epilogue: O[q][h*64+d] = O^T/l, 4 consecutive d per lane -> ushort4 ----
#pragma unroll
  for (int qt = 0; qt < 2; ++qt) {
    const float inv = 1.0f / l_i[qt];
    const int qrow = q0 + wq + qt * 16 + ln;
#pragma unroll
    for (int dt = 0; dt < 4; ++dt) {
      ushort4 st = {f2b(o[qt][dt][0] * inv), f2b(o[qt][dt][1] * inv),
                    f2b(o[qt][dt][2] * inv), f2b(o[qt][dt][3] * inv)};
      *(ushort4*)(O + ((size_t)b * S_LEN + qrow) * (NH * DH) + h * DH + dt * 16 + lg * 4) = st;
    }
  }
}

// ---------------------------------------------------------------------------
extern "C" void kernel_launch(void* const* d_in, const int* in_sizes, int n_in,
                              void* d_out, int out_size, void* d_ws, size_t ws_size,
                              hipStream_t stream) {
  const float* q    = (const float*)d_in[0];
  const float* mask = (const float*)d_in[1];
  const float* Wq   = (const float*)d_in[2];
  const float* Wk   = (const float*)d_in[3];
  const float* Wv   = (const float*)d_in[4];
  const float* Wo   = (const float*)d_in[5];
  float* out = (float*)d_out;

  const size_t M = (size_t)NB * S_LEN;  // 4096
  u16* p = (u16*)d_ws;
  u16* qb    = p; p += M * 1024;            // input, bf16
  u16* WqkT  = p; p += 1536 * 1024;         // [Wq^T; Wk^T]
  u16* WvT   = p; p += 512 * 1024;
  u16* WoT   = p; p += 1024 * 1024;
  u16* biasL = p; p += (size_t)NB * S_LEN * S_LEN;  // bf16 [b][q][key]
  u16* xqk   = p; p += M * 1536;            // fused QK projection
  u16* xvT   = p; p += 512 * M;             // (512, B*S) dim-major
  u16* Qr    = p; p += M * 1024;            // (B,H,S,D)
  u16* Kr    = p; p += M * 1024;
  u16* Oc    = p; p += M * 1024;            // attention out (B,S,1024) bf16

  dim3 blk(256);
  // prep
  cast_bf16<<<(M * 1024) / 1024, blk, 0, stream>>>(q, qb, (int)(M * 1024));
  transpose_cast<<<dim3(1024 / 32, 1024 / 32), blk, 0, stream>>>(Wq, WqkT, 1024, 1024);
  transpose_cast<<<dim3(512 / 32, 1024 / 32), blk, 0, stream>>>(Wk, WqkT + 1024 * 1024, 1024, 512);
  transpose_cast<<<dim3(512 / 32, 1024 / 32), blk, 0, stream>>>(Wv, WvT, 1024, 512);
  transpose_cast<<<dim3(1024 / 32, 1024 / 32), blk, 0, stream>>>(Wo, WoT, 1024, 1024);
  bias_prep<<<((int)(NB * S_LEN * S_LEN)) / 1024, blk, 0, stream>>>(
      mask, biasL, (int)(NB * S_LEN * S_LEN));

  // projections (bf16 MFMA)
  gemm_bt<1><<<dim3(1536 / 128, M / 128), blk, 0, stream>>>(qb, WqkT, xqk, M, 1536, 1024);
  // xvT = Wv^T @ q^T (swapped roles) -> (512, B*S) dim-major
  gemm_bt<1><<<dim3(M / 128, 512 / 128), blk, 0, stream>>>(WvT, qb, xvT, 512, M, 1024);

  // rope Q (with 0.5 fold), K -> (B,H,S,D)
  rope_qk<<<(NB * S_LEN * NH * 32) / 256, blk, 0, stream>>>(xqk, Qr, Kr);

  // fused attention
  flash_mfma<<<dim3(NB * NH, S_LEN / 128), blk, 0, stream>>>(Qr, Kr, xvT, biasL, Oc);

  // output projection (fp32 out)
  gemm_bt<0><<<dim3(1024 / 128, M / 128), blk, 0, stream>>>(Oc, WoT, out, M, 1024, 1024);
}

// Round 4
// 269.356 us; speedup vs baseline: 5.0077x; 1.1562x over previous
//
#include <hip/hip_runtime.h>
#include <math.h>

#define S_LEN 2048
#define NB 2
#define NH 16
#define DH 64

typedef unsigned short u16;
typedef unsigned int u32;
typedef __attribute__((ext_vector_type(8))) short bf16x8;
typedef __attribute__((ext_vector_type(4))) float f32x4;

__device__ __forceinline__ u16 f2b(float f) {
  u32 u = __float_as_uint(f);
  u += 0x7fffu + ((u >> 16) & 1u);
  return (u16)(u >> 16);
}
__device__ __forceinline__ float b2f(u16 u) { return __uint_as_float(((u32)u) << 16); }
__device__ __forceinline__ u32 packbf(float a, float b) {
  u32 ua = __float_as_uint(a) + 0x8000u;
  u32 ub = __float_as_uint(b) + 0x8000u;
  return (ua >> 16) | (ub & 0xffff0000u);
}

// async global(16B/lane) -> LDS (wave-uniform base + lane*16)
__device__ __forceinline__ void gl_lds16(const u16* g, u16* l) {
  __builtin_amdgcn_global_load_lds((const __attribute__((address_space(1))) void*)g,
                                   (__attribute__((address_space(3))) void*)l, 16, 0, 0);
}

// ---------------------------------------------------------------------------
__global__ __launch_bounds__(256) void cast_bf16(const float* __restrict__ in,
                                                 u16* __restrict__ out, int n) {
  int i = (blockIdx.x * 256 + threadIdx.x) * 4;
  if (i < n) {
    float4 v = *(const float4*)(in + i);
    ushort4 o = {f2b(v.x), f2b(v.y), f2b(v.z), f2b(v.w)};
    *(ushort4*)(out + i) = o;
  }
}

// W (K x N, f32) -> WT (N x K, bf16)
__global__ __launch_bounds__(256) void transpose_cast(const float* __restrict__ W,
                                                      u16* __restrict__ WT,
                                                      int K, int N) {
  __shared__ float t[32][33];
  const int tx = threadIdx.x & 31, ty = threadIdx.x >> 5;
  const int n0 = blockIdx.x * 32, k0 = blockIdx.y * 32;
#pragma unroll
  for (int i = 0; i < 4; ++i) t[ty + i * 8][tx] = W[(size_t)(k0 + ty + i * 8) * N + n0 + tx];
  __syncthreads();
#pragma unroll
  for (int i = 0; i < 4; ++i)
    WT[(size_t)(n0 + ty + i * 8) * K + k0 + tx] = f2b(t[tx][ty + i * 8]);
}

// bf16 (rows x 512 slice of stride instride) -> transposed (512 x rows)
__global__ __launch_bounds__(256) void transpose_b16(const u16* __restrict__ in,
                                                     u16* __restrict__ out,
                                                     int instride, int outstride) {
  __shared__ u16 t[32][33];
  const int tx = threadIdx.x & 31, ty = threadIdx.x >> 5;
  const int r0 = blockIdx.y * 32, c0 = blockIdx.x * 32;
#pragma unroll
  for (int i = 0; i < 4; ++i)
    t[ty + i * 8][tx] = in[(size_t)(r0 + ty + i * 8) * instride + c0 + tx];
  __syncthreads();
#pragma unroll
  for (int i = 0; i < 4; ++i)
    out[(size_t)(c0 + ty + i * 8) * outstride + r0 + tx] = t[tx][ty + i * 8];
}

// bias[b][q][key] = bf16(1 - 1/mask)
__global__ __launch_bounds__(256) void bias_prep(const float* __restrict__ mask,
                                                 u16* __restrict__ bias, int n) {
  int i = (blockIdx.x * 256 + threadIdx.x) * 4;
  if (i < n) {
    float4 v = *(const float4*)(mask + i);
    ushort4 o = {f2b(1.0f - 1.0f / v.x), f2b(1.0f - 1.0f / v.y),
                 f2b(1.0f - 1.0f / v.z), f2b(1.0f - 1.0f / v.w)};
    *(ushort4*)(bias + i) = o;
  }
}

// ---------------------------------------------------------------------------
// bf16 MFMA GEMM: C[M,N] = A(M,K) @ Bt(N,K)^T. 128x128 tile, BK=32, 4 waves.
// Staging via global_load_lds(16B). LDS unpadded 128x32; XOR swizzle
// chunk ^= (row>>1)&3 applied on the GLOBAL source address so frag
// ds_read_b128 is <=2-way conflict.
// ---------------------------------------------------------------------------
template <int BF16OUT>
__global__ __launch_bounds__(256) void gemm_bt(const u16* __restrict__ A,
                                               const u16* __restrict__ Bt,
                                               void* __restrict__ Cv,
                                               int M, int N, int K) {
  __shared__ __align__(16) u16 As[128 * 32];
  __shared__ __align__(16) u16 Bs[128 * 32];
  const int tid = threadIdx.x;
  const int w = tid >> 6, lane = tid & 63, lg = lane >> 4, ln = lane & 15;
  const int m0 = blockIdx.y * 128, n0 = blockIdx.x * 128;
  const int wm = (w & 1) * 64, wn = (w >> 1) * 64;

  // staging slots: call j covers slots j*256+tid; r=s>>2 (row), c=s&3 (16B chunk)
  const int s0 = tid, s1 = 256 + tid;
  const int r0 = s0 >> 2, cg0 = (s0 & 3) ^ ((r0 >> 1) & 3);
  const int r1 = s1 >> 2, cg1 = (s1 & 3) ^ ((r1 >> 1) & 3);
  u16* ldsA0 = As + w * 512;          // bytes: w*1024
  u16* ldsA1 = As + 2048 + w * 512;   // 4096 + w*1024 bytes
  u16* ldsB0 = Bs + w * 512;
  u16* ldsB1 = Bs + 2048 + w * 512;

  f32x4 acc[4][4];
#pragma unroll
  for (int i = 0; i < 4; ++i)
#pragma unroll
    for (int j = 0; j < 4; ++j) acc[i][j] = (f32x4)0.0f;

  for (int k0 = 0; k0 < K; k0 += 32) {
    __syncthreads();
    gl_lds16(A + (size_t)(m0 + r0) * K + k0 + cg0 * 8, ldsA0);
    gl_lds16(A + (size_t)(m0 + r1) * K + k0 + cg1 * 8, ldsA1);
    gl_lds16(Bt + (size_t)(n0 + r0) * K + k0 + cg0 * 8, ldsB0);
    gl_lds16(Bt + (size_t)(n0 + r1) * K + k0 + cg1 * 8, ldsB1);
    __syncthreads();

    bf16x8 af[4], bfr[4];
#pragma unroll
    for (int mt = 0; mt < 4; ++mt) {
      int rm = wm + mt * 16 + ln;
      af[mt] = *(const bf16x8*)&As[rm * 32 + ((lg ^ ((rm >> 1) & 3)) * 8)];
    }
#pragma unroll
    for (int nt = 0; nt < 4; ++nt) {
      int rn = wn + nt * 16 + ln;
      bfr[nt] = *(const bf16x8*)&Bs[rn * 32 + ((lg ^ ((rn >> 1) & 3)) * 8)];
    }
#pragma unroll
    for (int mt = 0; mt < 4; ++mt)
#pragma unroll
      for (int nt = 0; nt < 4; ++nt)
        acc[mt][nt] = __builtin_amdgcn_mfma_f32_16x16x32_bf16(af[mt], bfr[nt], acc[mt][nt], 0, 0, 0);
  }

#pragma unroll
  for (int mt = 0; mt < 4; ++mt)
#pragma unroll
    for (int nt = 0; nt < 4; ++nt)
#pragma unroll
      for (int r = 0; r < 4; ++r) {
        int row = m0 + wm + mt * 16 + lg * 4 + r;
        int col = n0 + wn + nt * 16 + ln;
        if (BF16OUT)
          ((u16*)Cv)[(size_t)row * N + col] = f2b(acc[mt][nt][r]);
        else
          ((float*)Cv)[(size_t)row * N + col] = acc[mt][nt][r];
      }
}

// ---------------------------------------------------------------------------
// RoPE from fused QKV projection (row stride 2048). Q scaled by 0.5.
// K element-repeat: source dim h*32+p -> output pair (2p,2p+1). Out (B,H,S,D).
// ---------------------------------------------------------------------------
__global__ __launch_bounds__(256) void rope_qk(const u16* __restrict__ xqkv,
                                               u16* __restrict__ Qr,
                                               u16* __restrict__ Kr) {
  const int idx = blockIdx.x * 256 + threadIdx.x;  // 2^21
  const int p = idx & 31;
  const int h = (idx >> 5) & (NH - 1);
  const int s = (idx >> 9) & (S_LEN - 1);
  const int b = idx >> 20;

  float theta = __powf(10.0f, -(float)p);
  float ang = (float)(s + 1) * theta;
  float sn, cs;
  __sincosf(ang, &sn, &cs);

  const size_t rowBase = ((size_t)b * S_LEN + s) * 2048;
  const size_t outBase = (((size_t)b * NH + h) * S_LEN + s) * DH + 2 * p;

  {
    u32 qv = *(const u32*)(xqkv + rowBase + h * 64 + 2 * p);
    float xe = b2f((u16)(qv & 0xffffu)), xo = b2f((u16)(qv >> 16));
    u32 o = (u32)f2b((xe * cs - xo * sn) * 0.5f) |
            ((u32)f2b((xe * sn + xo * cs) * 0.5f) << 16);
    *(u32*)(Qr + outBase) = o;
  }
  {
    float v = b2f(xqkv[rowBase + 1024 + h * 32 + p]);
    u32 o = (u32)f2b(v * cs - v * sn) | ((u32)f2b(v * sn + v * cs) << 16);
    *(u32*)(Kr + outBase) = o;
  }
}

// ---------------------------------------------------------------------------
// MFMA flash attention v2. Block = 256 thr (4 waves), Q-tile 64 (wave w owns
// q cols w*16..w*16+15), K-tile 64, grid 1024 blocks -> 4 blocks/CU.
// Q fragments loaded directly from global (no LDS). K/V staged via
// global_load_lds with global-side XOR swizzle. V element-repeat folded into
// the fragment row index (row = dt*8 + ln>>1) — V staged unduplicated (32 rows).
// S^T = K·Q^T (key reduction in-lane + 2 shuffles); P wave-private in LDS;
// O^T = V^T·P^T. LDS total 20 KB.
// ---------------------------------------------------------------------------
__global__ __launch_bounds__(256) void flash_mfma(const u16* __restrict__ Qr,
                                                  const u16* __restrict__ Kr,
                                                  const u16* __restrict__ xvT,
                                                  const u16* __restrict__ bias,
                                                  u16* __restrict__ O) {
  __shared__ __align__(16) u16 Ks[64 * 64];   // (key, d), swizzled chunks
  __shared__ __align__(16) u16 Vt[32 * 64];   // (src dim, key), swizzled
  __shared__ __align__(16) u16 Ps[4 * 16 * 64];  // per-wave P (16 q x 64 keys)

  const int tid = threadIdx.x;
  const int w = tid >> 6, lane = tid & 63, lg = lane >> 4, ln = lane & 15;
  const int bh = blockIdx.x, b = bh >> 4, h = bh & 15;
  const int q0 = blockIdx.y * 64;
  const int wq = w * 16;

  const u16* Kg = Kr + (size_t)bh * S_LEN * DH;
  const u16* Vg = xvT + (size_t)(h * 32) * (NB * S_LEN) + (size_t)b * S_LEN;
  const u16* Bg = bias + ((size_t)b * S_LEN + q0) * S_LEN;
  u16* Pw = &Ps[w * 1024];

  // Q fragments straight from global: row q0+wq+ln, chunk kh*32+lg*8
  bf16x8 aq[2];
  {
    const u16* Qg = Qr + ((size_t)bh * S_LEN + q0 + wq + ln) * DH;
    aq[0] = *(const bf16x8*)(Qg + lg * 8);
    aq[1] = *(const bf16x8*)(Qg + 32 + lg * 8);
  }

  // staging slot geometry
  const int rK0 = tid >> 3, cK0 = (tid & 7) ^ (rK0 & 7);          // K rows 0..31
  const int rK1 = (256 + tid) >> 3, cK1 = (tid & 7) ^ (rK1 & 7);  // K rows 32..63
  const int rV = tid >> 3, cV = (tid & 7) ^ (rV & 7);             // V rows 0..31
  u16* ldsK0 = Ks + w * 512;
  u16* ldsK1 = Ks + 2048 + w * 512;
  u16* ldsV = Vt + w * 512;

  float m_i = -1e30f, l_i = 0.0f;
  f32x4 o[4];
#pragma unroll
  for (int dt = 0; dt < 4; ++dt) o[dt] = (f32x4)0.0f;

  for (int kt = 0; kt < S_LEN / 64; ++kt) {
    // bias regs (global, overlaps with barrier wait)
    ushort4 braw[4];
#pragma unroll
    for (int kp = 0; kp < 4; ++kp)
      braw[kp] = *(const ushort4*)(Bg + (size_t)(wq + ln) * S_LEN + kt * 64 + kp * 16 + lg * 4);

    __syncthreads();  // prev iter LDS reads complete
    gl_lds16(Kg + (size_t)(kt * 64 + rK0) * DH + cK0 * 8, ldsK0);
    gl_lds16(Kg + (size_t)(kt * 64 + rK1) * DH + cK1 * 8, ldsK1);
    gl_lds16(Vg + (size_t)rV * (NB * S_LEN) + kt * 64 + cV * 8, ldsV);
    __syncthreads();

    // ---- S^T = K · Q^T ----
    f32x4 sab[4];
#pragma unroll
    for (int kp = 0; kp < 4; ++kp) {
      bf16x8 ak0 = *(const bf16x8*)&Ks[(kp * 16 + ln) * 64 + (((lg) ^ (ln & 7)) * 8)];
      bf16x8 ak1 = *(const bf16x8*)&Ks[(kp * 16 + ln) * 64 + (((4 + lg) ^ (ln & 7)) * 8)];
      f32x4 z = (f32x4)0.0f;
      z = __builtin_amdgcn_mfma_f32_16x16x32_bf16(ak0, aq[0], z, 0, 0, 0);
      sab[kp] = __builtin_amdgcn_mfma_f32_16x16x32_bf16(ak1, aq[1], z, 0, 0, 0);
    }

    // ---- online softmax (q = ln col) ----
    float mx = -1e30f;
#pragma unroll
    for (int kp = 0; kp < 4; ++kp) {
      const ushort4 bq = braw[kp];
      sab[kp][0] += b2f(bq.x);
      sab[kp][1] += b2f(bq.y);
      sab[kp][2] += b2f(bq.z);
      sab[kp][3] += b2f(bq.w);
#pragma unroll
      for (int r = 0; r < 4; ++r) mx = fmaxf(mx, sab[kp][r]);
    }
    mx = fmaxf(mx, __shfl_xor(mx, 16));
    mx = fmaxf(mx, __shfl_xor(mx, 32));
    const float mn = fmaxf(m_i, mx);
    const float alpha = __expf(m_i - mn);
    m_i = mn;
    float rs = 0.0f;
#pragma unroll
    for (int kp = 0; kp < 4; ++kp) {
      float e0 = __expf(sab[kp][0] - mn);
      float e1 = __expf(sab[kp][1] - mn);
      float e2 = __expf(sab[kp][2] - mn);
      float e3 = __expf(sab[kp][3] - mn);
      rs += (e0 + e1) + (e2 + e3);
      uint2 pp = {packbf(e0, e1), packbf(e2, e3)};
      *(uint2*)&Pw[ln * 64 + (((kp * 2 + (lg >> 1)) ^ (ln & 7)) * 8) + (lg & 1) * 4] = pp;
    }
    rs += __shfl_xor(rs, 16);
    rs += __shfl_xor(rs, 32);
    l_i = l_i * alpha + rs;
#pragma unroll
    for (int dt = 0; dt < 4; ++dt) o[dt] *= alpha;

    // ---- O^T += V^T · P^T (P wave-private: no barrier) ----
    bf16x8 bp0 = *(const bf16x8*)&Pw[ln * 64 + ((lg ^ (ln & 7)) * 8)];
    bf16x8 bp1 = *(const bf16x8*)&Pw[ln * 64 + (((4 + lg) ^ (ln & 7)) * 8)];
#pragma unroll
    for (int dt = 0; dt < 4; ++dt) {
      const int rv = dt * 8 + (ln >> 1);  // element-repeat fold
      bf16x8 av0 = *(const bf16x8*)&Vt[rv * 64 + ((lg ^ (rv & 7)) * 8)];
      bf16x8 av1 = *(const bf16x8*)&Vt[rv * 64 + (((4 + lg) ^ (rv & 7)) * 8)];
      o[dt] = __builtin_amdgcn_mfma_f32_16x16x32_bf16(av0, bp0, o[dt], 0, 0, 0);
      o[dt] = __builtin_amdgcn_mfma_f32_16x16x32_bf16(av1, bp1, o[dt], 0, 0, 0);
    }
  }

  // ---- epilogue: O[q][h*64+d] ----
  const float inv = 1.0f / l_i;
  const int qrow = q0 + wq + ln;
#pragma unroll
  for (int dt = 0; dt < 4; ++dt) {
    ushort4 st = {f2b(o[dt][0] * inv), f2b(o[dt][1] * inv),
                  f2b(o[dt][2] * inv), f2b(o[dt][3] * inv)};
    *(ushort4*)(O + ((size_t)b * S_LEN + qrow) * (NH * DH) + h * DH + dt * 16 + lg * 4) = st;
  }
}

// ---------------------------------------------------------------------------
extern "C" void kernel_launch(void* const* d_in, const int* in_sizes, int n_in,
                              void* d_out, int out_size, void* d_ws, size_t ws_size,
                              hipStream_t stream) {
  const float* q    = (const float*)d_in[0];
  const float* mask = (const float*)d_in[1];
  const float* Wq   = (const float*)d_in[2];
  const float* Wk   = (const float*)d_in[3];
  const float* Wv   = (const float*)d_in[4];
  const float* Wo   = (const float*)d_in[5];
  float* out = (float*)d_out;

  const size_t M = (size_t)NB * S_LEN;  // 4096
  u16* p = (u16*)d_ws;
  u16* qb     = p; p += M * 1024;            // input bf16
  u16* WqkvT  = p; p += 2048 * 1024;         // [Wq^T; Wk^T; Wv^T]
  u16* WoT    = p; p += 1024 * 1024;
  u16* biasL  = p; p += (size_t)NB * S_LEN * S_LEN;  // [b][q][key] bf16
  u16* xqkv   = p; p += M * 2048;            // fused QKV projection
  u16* xvT    = p; p += 512 * M;             // (512, B*S) dim-major
  u16* Qr     = p; p += M * 1024;            // (B,H,S,D)
  u16* Kr     = p; p += M * 1024;
  u16* Oc     = p; p += M * 1024;            // attention out (B,S,1024) bf16

  dim3 blk(256);
  cast_bf16<<<(M * 1024) / 1024, blk, 0, stream>>>(q, qb, (int)(M * 1024));
  transpose_cast<<<dim3(32, 32), blk, 0, stream>>>(Wq, WqkvT, 1024, 1024);
  transpose_cast<<<dim3(16, 32), blk, 0, stream>>>(Wk, WqkvT + 1024 * 1024, 1024, 512);
  transpose_cast<<<dim3(16, 32), blk, 0, stream>>>(Wv, WqkvT + 1536 * 1024, 1024, 512);
  transpose_cast<<<dim3(32, 32), blk, 0, stream>>>(Wo, WoT, 1024, 1024);
  bias_prep<<<((int)(NB * S_LEN * S_LEN)) / 1024, blk, 0, stream>>>(
      mask, biasL, (int)(NB * S_LEN * S_LEN));

  // fused QKV projection: (4096 x 2048)
  gemm_bt<1><<<dim3(2048 / 128, M / 128), blk, 0, stream>>>(qb, WqkvT, xqkv, M, 2048, 1024);
  // xvT = transpose of xqkv[:, 1536:2048]
  transpose_b16<<<dim3(512 / 32, M / 32), blk, 0, stream>>>(xqkv + 1536, xvT, 2048, (int)M);
  // rope Q (0.5 folded), K -> (B,H,S,D)
  rope_qk<<<(NB * S_LEN * NH * 32) / 256, blk, 0, stream>>>(xqkv, Qr, Kr);
  // fused attention
  flash_mfma<<<dim3(NB * NH, S_LEN / 64), blk, 0, stream>>>(Qr, Kr, xvT, biasL, Oc);
  // output projection (fp32 out)
  gemm_bt<0><<<dim3(1024 / 128, M / 128), blk, 0, stream>>>(Oc, WoT, out, M, 1024, 1024);
}